// Round 3
// baseline (1952.852 us; speedup 1.0000x reference)
//
#include <hip/hip_runtime.h>
#include <hip/hip_bf16.h>

// Problem constants
#define B_    32
#define S_    16
#define L_    64
#define E_    300
#define P_    100
#define H_    256
#define DATT  612
#define NS    512      // B*S
#define M1    32768    // NS*L

typedef __hip_bfloat16 hbf;
typedef __attribute__((ext_vector_type(8))) short bf16x8;
typedef __attribute__((ext_vector_type(4))) float f32x4;
typedef __attribute__((ext_vector_type(4))) int i32x4;

__device__ __forceinline__ float u2f(unsigned short u) {
    unsigned int x = ((unsigned int)u) << 16;
    return __builtin_bit_cast(float, x);
}
__device__ __forceinline__ unsigned short f2u(float f) {
    return __builtin_bit_cast(unsigned short, __float2bfloat16(f));
}
__device__ __forceinline__ float sigm(float x) { return 1.0f / (1.0f + __expf(-x)); }
__device__ __forceinline__ float tanh_f(float x) {
    return 1.0f - 2.0f / (__expf(2.0f * x) + 1.0f);
}

// ---------------------------------------------------------------------------
// Prep: Wih concat [2048][Kdst] bf16 (rows 0..1023 fwd, 1024..2047 bwd), 0-pad K
// ---------------------------------------------------------------------------
__global__ void k_prep_wih(const float* __restrict__ wf, const float* __restrict__ wb,
                           int Ksrc, int Kdst, unsigned short* __restrict__ out) {
    int j = blockIdx.x;
    const float* src = (j < 1024) ? (wf + (size_t)j * Ksrc) : (wb + (size_t)(j - 1024) * Ksrc);
    unsigned short* o = out + (size_t)j * Kdst;
    for (int c = threadIdx.x; c < Kdst; c += blockDim.x)
        o[c] = (c < Ksrc) ? f2u(src[c]) : (unsigned short)0;
}

__global__ void k_cat_bias(const float* __restrict__ a, const float* __restrict__ b,
                           float* __restrict__ dst) {
    int i = blockIdx.x * 256 + threadIdx.x;   // 0..2047
    dst[i] = (i < 1024) ? a[i] : b[i - 1024];
}

// whh_sw[d][kt][n][kk] = Whh_d[n][kt*32+kk]  (bf16, fragment-ready)
__global__ void k_prep_whh(const float* __restrict__ w0, const float* __restrict__ w1,
                           const float* __restrict__ w2, const float* __restrict__ w3,
                           unsigned short* __restrict__ out) {
    const float* w;
    switch (blockIdx.y) { case 0: w = w0; break; case 1: w = w1; break;
                          case 2: w = w2; break; default: w = w3; }
    int n = blockIdx.x, tid = threadIdx.x;
    int kt = tid >> 5, kk = tid & 31;
    out[(((size_t)blockIdx.y * 8 + kt) * 1024 + n) * 32 + kk] = f2u(w[(size_t)n * 256 + tid]);
}

// Wt[n][k] = W[k][n], 640x640 zero-padded bf16
__global__ void k_prep_attw(const float* __restrict__ W, unsigned short* __restrict__ out) {
    int n = blockIdx.x;
    for (int k = threadIdx.x; k < 640; k += blockDim.x)
        out[(size_t)n * 640 + k] = (n < DATT && k < DATT) ? f2u(W[(size_t)k * DATT + n]) : (unsigned short)0;
}

// x = [emb[tok] | wpe[wpos] | 0pad] -> bf16 [32768][416]
__global__ void k_gather_x(const int* __restrict__ tok, const int* __restrict__ wpos,
                           const float* __restrict__ emb, const float* __restrict__ wpe,
                           unsigned short* __restrict__ x) {
    int i = blockIdx.x;
    int t = tok[i], p = wpos[i];
    const float* er = emb + (size_t)t * E_;
    const float* pr = wpe + (size_t)p * P_;
    unsigned short* xr = x + (size_t)i * 416;
    for (int c = threadIdx.x; c < 416; c += blockDim.x) {
        float v = (c < E_) ? er[c] : (c < 400 ? pr[c - E_] : 0.f);
        xr[c] = f2u(v);
    }
}

// ---------------------------------------------------------------------------
// MFMA GEMM: C[M][2048] = bf16(A[M][lda] @ W[2048][lda]^T + bias)
// 128x128 tile, BK=32, 256 threads (2x2 waves, each 64x64)
// ---------------------------------------------------------------------------
__global__ __launch_bounds__(256) void k_gemm_bias(
        const unsigned short* __restrict__ A, int lda,
        const unsigned short* __restrict__ W, const float* __restrict__ bias,
        unsigned short* __restrict__ C, int nkt) {
    __shared__ __align__(16) unsigned short As[128][40];
    __shared__ __align__(16) unsigned short Bs[128][40];
    int tid = threadIdx.x;
    int lane = tid & 63, wave = tid >> 6;
    int wm = wave >> 1, wn = wave & 1;
    int i0 = blockIdx.y * 128, n0 = blockIdx.x * 128;
    f32x4 acc[4][4] = {};
    int r = tid >> 2, kc = (tid & 3) * 8;
    for (int kt = 0; kt < nkt; ++kt) {
        int k0 = kt * 32;
        #pragma unroll
        for (int p = 0; p < 2; ++p) {
            int rr = r + p * 64;
            *(i32x4*)&As[rr][kc] = *(const i32x4*)&A[(size_t)(i0 + rr) * lda + k0 + kc];
            *(i32x4*)&Bs[rr][kc] = *(const i32x4*)&W[(size_t)(n0 + rr) * lda + k0 + kc];
        }
        __syncthreads();
        bf16x8 a[4], b[4];
        int arow = wm * 64 + (lane & 15);
        int brow = wn * 64 + (lane & 15);
        int kq = (lane >> 4) * 8;
        #pragma unroll
        for (int mi = 0; mi < 4; ++mi) a[mi] = *(const bf16x8*)&As[arow + mi * 16][kq];
        #pragma unroll
        for (int nj = 0; nj < 4; ++nj) b[nj] = *(const bf16x8*)&Bs[brow + nj * 16][kq];
        #pragma unroll
        for (int mi = 0; mi < 4; ++mi)
            #pragma unroll
            for (int nj = 0; nj < 4; ++nj)
                acc[mi][nj] = __builtin_amdgcn_mfma_f32_16x16x32_bf16(a[mi], b[nj], acc[mi][nj], 0, 0, 0);
        __syncthreads();
    }
    int q = lane >> 4;
    #pragma unroll
    for (int nj = 0; nj < 4; ++nj) {
        int col = n0 + wn * 64 + nj * 16 + (lane & 15);
        float bb = bias[col];
        #pragma unroll
        for (int mi = 0; mi < 4; ++mi)
            #pragma unroll
            for (int rr2 = 0; rr2 < 4; ++rr2) {
                int grow = i0 + wm * 64 + mi * 16 + q * 4 + rr2;
                C[(size_t)grow * 2048 + col] = f2u(acc[mi][nj][rr2] + bb);
            }
    }
}

// ---------------------------------------------------------------------------
// MFMA attention score: score[i] += proj . tanh(z[i] @ W + bias) over 128-col slice
// ---------------------------------------------------------------------------
__global__ __launch_bounds__(256) void k_attn_mfma(
        const unsigned short* __restrict__ Hsrc,
        const unsigned short* __restrict__ xpos,   // mode0: [M][416], pos at col 300
        const float* __restrict__ spe, const int* __restrict__ spos,  // mode1
        const unsigned short* __restrict__ Wt,     // [640][640] bf16 (n-major)
        const float* __restrict__ bias, const float* __restrict__ proj,
        float* __restrict__ score, int mode) {
    __shared__ __align__(16) unsigned short As[128][40];
    __shared__ __align__(16) unsigned short Bs[128][40];
    int tid = threadIdx.x;
    int lane = tid & 63, wave = tid >> 6;
    int wm = wave >> 1, wn = wave & 1;
    int i0 = blockIdx.y * 128, n0 = blockIdx.x * 128;
    f32x4 acc[4][4] = {};
    int r = tid >> 2, kc = (tid & 3) * 8;
    for (int kt = 0; kt < 20; ++kt) {
        int k0 = kt * 32;
        #pragma unroll
        for (int p = 0; p < 2; ++p) {
            int rr = r + p * 64;
            if (kt < 16) {
                *(i32x4*)&As[rr][kc] = *(const i32x4*)&Hsrc[(size_t)(i0 + rr) * 512 + k0 + kc];
            } else {
                int grow = i0 + rr;
                #pragma unroll
                for (int e = 0; e < 8; ++e) {
                    int k = k0 + kc + e;
                    int pp = k - 512;
                    unsigned short v = 0;
                    if (pp < P_) {
                        if (mode == 0) v = xpos[(size_t)grow * 416 + 300 + pp];
                        else           v = f2u(spe[(size_t)spos[grow] * P_ + pp]);
                    }
                    As[rr][kc + e] = v;
                }
            }
            *(i32x4*)&Bs[rr][kc] = *(const i32x4*)&Wt[(size_t)(n0 + rr) * 640 + k0 + kc];
        }
        __syncthreads();
        bf16x8 a[4], b[4];
        int arow = wm * 64 + (lane & 15);
        int brow = wn * 64 + (lane & 15);
        int kq = (lane >> 4) * 8;
        #pragma unroll
        for (int mi = 0; mi < 4; ++mi) a[mi] = *(const bf16x8*)&As[arow + mi * 16][kq];
        #pragma unroll
        for (int nj = 0; nj < 4; ++nj) b[nj] = *(const bf16x8*)&Bs[brow + nj * 16][kq];
        #pragma unroll
        for (int mi = 0; mi < 4; ++mi)
            #pragma unroll
            for (int nj = 0; nj < 4; ++nj)
                acc[mi][nj] = __builtin_amdgcn_mfma_f32_16x16x32_bf16(a[mi], b[nj], acc[mi][nj], 0, 0, 0);
        __syncthreads();
    }
    float srow[4][4] = {};
    int q = lane >> 4;
    #pragma unroll
    for (int nj = 0; nj < 4; ++nj) {
        int col = n0 + wn * 64 + nj * 16 + (lane & 15);
        if (col < DATT) {
            float bb = bias[col], pp = proj[col];
            #pragma unroll
            for (int mi = 0; mi < 4; ++mi)
                #pragma unroll
                for (int rr2 = 0; rr2 < 4; ++rr2)
                    srow[mi][rr2] += pp * tanh_f(acc[mi][nj][rr2] + bb);
        }
    }
    #pragma unroll
    for (int mi = 0; mi < 4; ++mi)
        #pragma unroll
        for (int rr2 = 0; rr2 < 4; ++rr2) {
            float v = srow[mi][rr2];
            v += __shfl_xor(v, 1); v += __shfl_xor(v, 2);
            v += __shfl_xor(v, 4); v += __shfl_xor(v, 8);
            if ((lane & 15) == 0)
                atomicAdd(&score[i0 + wm * 64 + mi * 16 + q * 4 + rr2], v);
        }
}

// ---------------------------------------------------------------------------
// Weight-stationary cooperative LSTM.
// 4 blocks per 16-seq group; block owns 64 units (cols u..u+63 of each gate),
// Whh slice (128KB) resident in LDS. h exchanged per step via global hbuf
// slabs (one per (group,t)) + agent-scope flags. Launched cooperatively,
// grid <= 256 = #CUs, 1 block/CU.
// ---------------------------------------------------------------------------
__global__ __launch_bounds__(256) void k_lstm_coop(
        const unsigned short* __restrict__ g,    // [(seq)*T+t][2048] bf16 (bias folded)
        const unsigned short* __restrict__ whh,  // [2][8][1024][32] bf16
        unsigned short* __restrict__ out,        // [(seq)*T+t][512] bf16
        unsigned short* __restrict__ hbuf,       // [ngroups][T][16][256] bf16
        int* __restrict__ flags,                 // [ngroups][T]
        float* __restrict__ finalh,              // optional, stride 1024
        int T, int ngroups, int mapmode) {
    extern __shared__ __align__(16) char smem[];
    unsigned short* wlds = (unsigned short*)smem;               // 128KB
    unsigned short* gpre = (unsigned short*)(smem + 131072);    // [16][260] bf16
    const int tid = threadIdx.x;
    const int lane = tid & 63, w = tid >> 6;
    const int q = lane >> 4, l16 = lane & 15;
    int bid = blockIdx.x, s, grp;
    if (mapmode == 0) { int x = bid & 7, y = bid >> 3; s = y & 3; grp = (y >> 2) * 8 + x; }
    else              { grp = bid & 3; s = bid >> 2; }
    const int half = ngroups >> 1;
    const int dir = (grp >= half) ? 1 : 0;
    const int seq0 = (grp - dir * half) * 16;
    const unsigned short* wh = whh + (size_t)dir * (8 * 1024 * 32);

    // stage this block's Whh slice into LDS (fragment-ready, lane-linear)
    #pragma unroll
    for (int gb = 0; gb < 4; ++gb) {
        int col = gb * 256 + s * 64 + w * 16 + l16;
        #pragma unroll
        for (int kt = 0; kt < 8; ++kt) {
            i32x4 v = *(const i32x4*)&wh[((size_t)kt * 1024 + col) * 32 + q * 8];
            *(i32x4*)&wlds[((((w * 4 + gb) * 8) + kt) << 9) + lane * 8] = v;
        }
    }
    float c[4] = {0.f, 0.f, 0.f, 0.f};
    __syncthreads();

    unsigned short* hb_g = hbuf + (size_t)grp * T * 4096;
    int* flag_g = flags + grp * T;
    const int unit = s * 64 + w * 16 + l16;

    for (int t = 0; t < T; ++t) {
        const int ti = dir ? (T - 1 - t) : t;
        // (1) issue g_pre loads early (independent of h)
        i32x4 gld[2];
        int goff[2];
        #pragma unroll
        for (int it = 0; it < 2; ++it) {
            int idx = tid + it * 256;            // 0..511
            int sq = idx >> 5;
            int gb = (idx >> 3) & 3;
            int oc = idx & 7;
            size_t row = (size_t)(seq0 + sq) * T + ti;
            int gcol = dir * 1024 + gb * 256 + s * 64 + oc * 8;
            gld[it] = *(const i32x4*)&g[row * 2048 + gcol];
            goff[it] = sq * 260 + gb * 64 + oc * 8;
        }
        // (2) wait for previous step's h
        if (t > 0) {
            if (tid == 0) {
                while (__hip_atomic_load(&flag_g[t - 1], __ATOMIC_ACQUIRE,
                                         __HIP_MEMORY_SCOPE_AGENT) < 4)
                    __builtin_amdgcn_s_sleep(2);
            }
            __syncthreads();
        }
        // (3) park g_pre in LDS (padded row 260 -> conflict-light reads later)
        #pragma unroll
        for (int it = 0; it < 2; ++it)
            *(i32x4*)&gpre[goff[it]] = gld[it];
        // (4) recurrent matvec: acc[gb] = h(t-1) @ Wslice
        f32x4 acc[4] = {};
        if (t > 0) {
            const unsigned short* hb = hb_g + (size_t)(t - 1) * 4096;
            bf16x8 a[8];
            #pragma unroll
            for (int kt = 0; kt < 8; ++kt)
                a[kt] = *(const bf16x8*)&hb[l16 * 256 + kt * 32 + q * 8];
            #pragma unroll
            for (int kt = 0; kt < 8; ++kt)
                #pragma unroll
                for (int gb = 0; gb < 4; ++gb) {
                    bf16x8 b = *(const bf16x8*)&wlds[((((w * 4 + gb) * 8) + kt) << 9) + lane * 8];
                    acc[gb] = __builtin_amdgcn_mfma_f32_16x16x32_bf16(a[kt], b, acc[gb], 0, 0, 0);
                }
        }
        __syncthreads();   // gpre visible to all waves
        // (5) cell update: lane owns (unit, 4 seqs); all 4 gates in-register
        unsigned short* hw = hb_g + (size_t)t * 4096;
        #pragma unroll
        for (int rr = 0; rr < 4; ++rr) {
            int sq = q * 4 + rr;
            int gbase = sq * 260 + w * 16 + l16;
            float ig = acc[0][rr] + u2f(gpre[gbase]);
            float fg = acc[1][rr] + u2f(gpre[gbase + 64]);
            float gg = acc[2][rr] + u2f(gpre[gbase + 128]);
            float og = acc[3][rr] + u2f(gpre[gbase + 192]);
            ig = sigm(ig); fg = sigm(fg); gg = tanh_f(gg); og = sigm(og);
            c[rr] = fg * c[rr] + ig * gg;
            float hn = og * tanh_f(c[rr]);
            unsigned short hnb = f2u(hn);
            hw[sq * 256 + unit] = hnb;
            out[((size_t)(seq0 + sq) * T + ti) * 512 + dir * 256 + unit] = hnb;
            if (finalh && t == T - 1)
                finalh[(size_t)(seq0 + sq) * 1024 + dir * 256 + unit] = hn;
        }
        // (6) publish: barrier drains all waves' stores, then release-flag
        __syncthreads();
        if (tid == 0) {
            __threadfence();
            __hip_atomic_fetch_add(&flag_g[t], 1, __ATOMIC_RELEASE,
                                   __HIP_MEMORY_SCOPE_AGENT);
        }
    }
}

// ---------------------------------------------------------------------------
// word softmax over L=64 + pool -> sx = [sen_vec | spe | 0] bf16 [512][640]
// ---------------------------------------------------------------------------
__global__ void k_pool_word(const float* __restrict__ score, const unsigned short* __restrict__ sen_out,
                            const float* __restrict__ spe, const int* __restrict__ spos,
                            unsigned short* __restrict__ sx) {
    int n = blockIdx.x, tid = threadIdx.x;
    __shared__ float a_lds[64];
    if (tid < 64) {
        float sc = score[n * 64 + tid];
        float m = sc;
        #pragma unroll
        for (int off = 32; off >= 1; off >>= 1) m = fmaxf(m, __shfl_xor(m, off));
        float e = __expf(sc - m);
        float s = e;
        #pragma unroll
        for (int off = 32; off >= 1; off >>= 1) s += __shfl_xor(s, off);
        a_lds[tid] = e / s;
    }
    __syncthreads();
    for (int h = tid; h < 512; h += blockDim.x) {
        float acc = 0.f;
        const unsigned short* base = sen_out + (size_t)n * 64 * 512 + h;
        #pragma unroll 8
        for (int t = 0; t < 64; ++t) acc += a_lds[t] * u2f(base[(size_t)t * 512]);
        sx[(size_t)n * 640 + h] = f2u(acc);
    }
    int sp = spos[n];
    for (int p2 = tid; p2 < 128; p2 += blockDim.x)
        sx[(size_t)n * 640 + 512 + p2] = (p2 < P_) ? f2u(spe[(size_t)sp * P_ + p2]) : (unsigned short)0;
}

// sentence softmax over S=16 + pool -> feats[:, 0:512]
__global__ void k_pool_sent(const float* __restrict__ score, const unsigned short* __restrict__ doc_out,
                            float* __restrict__ feats) {
    int n = blockIdx.x, tid = threadIdx.x;
    __shared__ float a_lds[16];
    if (tid < 16) {
        float sc = score[n * 16 + tid];
        float m = sc;
        #pragma unroll
        for (int off = 8; off >= 1; off >>= 1) m = fmaxf(m, __shfl_xor(m, off));
        float e = __expf(sc - m);
        float s = e;
        #pragma unroll
        for (int off = 8; off >= 1; off >>= 1) s += __shfl_xor(s, off);
        a_lds[tid] = e / s;
    }
    __syncthreads();
    for (int h = tid; h < 512; h += blockDim.x) {
        float acc = 0.f;
        const unsigned short* base = doc_out + (size_t)n * 16 * 512 + h;
        #pragma unroll
        for (int t = 0; t < 16; ++t) acc += a_lds[t] * u2f(base[(size_t)t * 512]);
        feats[(size_t)n * 1024 + h] = acc;
    }
}

__global__ void k_dense(const float* __restrict__ feats, const float* __restrict__ W,
                        const float* __restrict__ bias, float* __restrict__ out) {
    int b = blockIdx.x, lane = threadIdx.x;
    for (int p = 0; p < 3; ++p) {
        float acc = 0.f;
        for (int k = lane; k < 1024; k += 64)
            acc += feats[(size_t)b * 1024 + k] * W[(size_t)p * 1024 + k];
        #pragma unroll
        for (int off = 32; off >= 1; off >>= 1) acc += __shfl_xor(acc, off);
        if (lane == 0) out[b * 3 + p] = acc + bias[p];
    }
}

// ---------------------------------------------------------------------------
extern "C" void kernel_launch(void* const* d_in, const int* in_sizes, int n_in,
                              void* d_out, int out_size, void* d_ws, size_t ws_size,
                              hipStream_t stream) {
    const int*   tok    = (const int*)d_in[0];
    const int*   wpos   = (const int*)d_in[1];
    const int*   spos   = (const int*)d_in[2];
    const float* emb    = (const float*)d_in[3];
    const float* wpet   = (const float*)d_in[4];
    const float* spet   = (const float*)d_in[5];
    const float* wWih_f = (const float*)d_in[6];
    const float* wWhh_f = (const float*)d_in[7];
    const float* wb_f   = (const float*)d_in[8];
    const float* wWih_b = (const float*)d_in[9];
    const float* wWhh_b = (const float*)d_in[10];
    const float* wb_b   = (const float*)d_in[11];
    const float* sWih_f = (const float*)d_in[12];
    const float* sWhh_f = (const float*)d_in[13];
    const float* sb_f   = (const float*)d_in[14];
    const float* sWih_b = (const float*)d_in[15];
    const float* sWhh_b = (const float*)d_in[16];
    const float* sb_b   = (const float*)d_in[17];
    const float* word_W = (const float*)d_in[18];
    const float* word_bias = (const float*)d_in[19];
    const float* word_proj = (const float*)d_in[20];
    const float* sent_W = (const float*)d_in[21];
    const float* sent_bias = (const float*)d_in[22];
    const float* sent_proj = (const float*)d_in[23];
    const float* dense_W = (const float*)d_in[24];
    const float* dense_b = (const float*)d_in[25];

    char* p = (char*)d_ws;
    auto alloc = [&](size_t bytes) -> void* {
        void* r = (void*)p;
        p += (bytes + 255) & ~(size_t)255;
        return r;
    };
    unsigned short* x_bf    = (unsigned short*)alloc((size_t)M1 * 416 * 2);
    unsigned short* g_bf    = (unsigned short*)alloc((size_t)M1 * 2048 * 2);
    unsigned short* sen_out = (unsigned short*)alloc((size_t)M1 * 512 * 2);
    float*          scores  = (float*)alloc((size_t)(M1 + NS) * 4);
    unsigned short* sx      = (unsigned short*)alloc((size_t)NS * 640 * 2);
    unsigned short* sg      = (unsigned short*)alloc((size_t)NS * 2048 * 2);
    unsigned short* doc_out = (unsigned short*)alloc((size_t)NS * 512 * 2);
    float*          feats   = (float*)alloc((size_t)B_ * 1024 * 4);
    unsigned short* wih_w   = (unsigned short*)alloc((size_t)2048 * 416 * 2);
    unsigned short* wih_s   = (unsigned short*)alloc((size_t)2048 * 640 * 2);
    float*          bias_w  = (float*)alloc(2048 * 4);
    float*          bias_s  = (float*)alloc(2048 * 4);
    unsigned short* whh_sw  = (unsigned short*)alloc((size_t)4 * 8 * 1024 * 32 * 2);
    unsigned short* attw_w  = (unsigned short*)alloc((size_t)640 * 640 * 2);
    unsigned short* attw_s  = (unsigned short*)alloc((size_t)640 * 640 * 2);
    unsigned short* hb_w    = (unsigned short*)alloc((size_t)64 * 64 * 4096 * 2);  // 33.5MB
    unsigned short* hb_s    = (unsigned short*)alloc((size_t)4 * 16 * 4096 * 2);
    int*            flags   = (int*)alloc((size_t)(64 * 64 + 4 * 16) * 4);
    float* wscore = scores;
    float* sscore = scores + M1;
    int* flag_s = flags + 64 * 64;

    // ---- prep ----
    hipMemsetAsync(scores, 0, (size_t)(M1 + NS) * 4, stream);
    hipMemsetAsync(flags, 0, (size_t)(64 * 64 + 4 * 16) * 4, stream);
    k_prep_wih<<<2048, 256, 0, stream>>>(wWih_f, wWih_b, 400, 416, wih_w);
    k_prep_wih<<<2048, 256, 0, stream>>>(sWih_f, sWih_b, 612, 640, wih_s);
    k_cat_bias<<<8, 256, 0, stream>>>(wb_f, wb_b, bias_w);
    k_cat_bias<<<8, 256, 0, stream>>>(sb_f, sb_b, bias_s);
    k_prep_whh<<<dim3(1024, 4), 256, 0, stream>>>(wWhh_f, wWhh_b, sWhh_f, sWhh_b, whh_sw);
    k_prep_attw<<<640, 256, 0, stream>>>(word_W, attw_w);
    k_prep_attw<<<640, 256, 0, stream>>>(sent_W, attw_s);
    k_gather_x<<<M1, 256, 0, stream>>>(tok, wpos, emb, wpet, x_bf);

    const unsigned int lstm_lds = 131072 + 16 * 260 * 2;   // 139392 B

    // ---- word level ----
    k_gemm_bias<<<dim3(16, 256), 256, 0, stream>>>(x_bf, 416, wih_w, bias_w, g_bf, 13);
    {
        const unsigned short* ga = g_bf;
        const unsigned short* wa = whh_sw;
        unsigned short* oa = sen_out;
        unsigned short* ha = hb_w;
        int* fa = flags;
        float* fh = nullptr;
        int T = L_, ng = 64, mm = 0;
        void* args[] = { &ga, &wa, &oa, &ha, &fa, &fh, &T, &ng, &mm };
        hipLaunchCooperativeKernel((const void*)k_lstm_coop, dim3(256), dim3(256),
                                   args, lstm_lds, stream);
    }
    k_attn_mfma<<<dim3(5, 256), 256, 0, stream>>>(sen_out, x_bf, nullptr, nullptr,
                                                  attw_w, word_bias, word_proj, wscore, 0);
    k_pool_word<<<512, 256, 0, stream>>>(wscore, sen_out, spet, spos, sx);

    // ---- sentence level ----
    k_gemm_bias<<<dim3(16, 4), 256, 0, stream>>>(sx, 640, wih_s, bias_s, sg, 20);
    {
        const unsigned short* ga = sg;
        const unsigned short* wa = whh_sw + (size_t)2 * 8 * 1024 * 32;
        unsigned short* oa = doc_out;
        unsigned short* ha = hb_s;
        int* fa = flag_s;
        float* fh = feats + 512;
        int T = S_, ng = 4, mm = 1;
        void* args[] = { &ga, &wa, &oa, &ha, &fa, &fh, &T, &ng, &mm };
        hipLaunchCooperativeKernel((const void*)k_lstm_coop, dim3(16), dim3(256),
                                   args, lstm_lds, stream);
    }
    k_attn_mfma<<<dim3(5, 4), 256, 0, stream>>>(doc_out, nullptr, spet, spos,
                                                attw_s, sent_bias, sent_proj, sscore, 1);
    k_pool_sent<<<32, 256, 0, stream>>>(sscore, doc_out, feats);

    // ---- classifier ----
    k_dense<<<32, 64, 0, stream>>>(feats, dense_W, dense_b, (float*)d_out);
}

// Round 5
// 884.872 us; speedup vs baseline: 2.2069x; 2.2069x over previous
//
#include <hip/hip_runtime.h>
#include <hip/hip_bf16.h>

// Problem constants
#define B_    32
#define S_    16
#define L_    64
#define E_    300
#define P_    100
#define H_    256
#define DATT  612
#define NS    512      // B*S
#define M1    32768    // NS*L

typedef __hip_bfloat16 hbf;
typedef __attribute__((ext_vector_type(8))) short bf16x8;
typedef __attribute__((ext_vector_type(4))) float f32x4;
typedef __attribute__((ext_vector_type(4))) int i32x4;

__device__ __forceinline__ float u2f(unsigned short u) {
    unsigned int x = ((unsigned int)u) << 16;
    return __builtin_bit_cast(float, x);
}
__device__ __forceinline__ unsigned short f2u(float f) {
    return __builtin_bit_cast(unsigned short, __float2bfloat16(f));
}
__device__ __forceinline__ float sigm(float x) { return 1.0f / (1.0f + __expf(-x)); }
__device__ __forceinline__ float tanh_f(float x) {
    return 1.0f - 2.0f / (__expf(2.0f * x) + 1.0f);
}

// ---------------------------------------------------------------------------
// Prep: Wih concat [2048][Kdst] bf16 (rows 0..1023 fwd, 1024..2047 bwd), 0-pad K
// ---------------------------------------------------------------------------
__global__ void k_prep_wih(const float* __restrict__ wf, const float* __restrict__ wb,
                           int Ksrc, int Kdst, unsigned short* __restrict__ out) {
    int j = blockIdx.x;
    const float* src = (j < 1024) ? (wf + (size_t)j * Ksrc) : (wb + (size_t)(j - 1024) * Ksrc);
    unsigned short* o = out + (size_t)j * Kdst;
    for (int c = threadIdx.x; c < Kdst; c += blockDim.x)
        o[c] = (c < Ksrc) ? f2u(src[c]) : (unsigned short)0;
}

__global__ void k_cat_bias(const float* __restrict__ a, const float* __restrict__ b,
                           float* __restrict__ dst) {
    int i = blockIdx.x * 256 + threadIdx.x;   // 0..2047
    dst[i] = (i < 1024) ? a[i] : b[i - 1024];
}

// ---------------------------------------------------------------------------
// Prep Whh into per-(wave,colfrag,ktile) MFMA-fragment order:
// frag fi = w*64 + cf*8 + kt  (w:wave 0..7, cf: u16*4+gb 0..7, kt 0..7)
// element: out[(slot*512 + fi)*512 + lane*8 + e] = Whh[col][k]
//   col = (cf&3)*256 + w*32 + (cf>>2)*16 + (lane&15),  k = kt*32 + (lane>>4)*8 + e
// ---------------------------------------------------------------------------
__global__ void k_prep_whhr(const float* __restrict__ w0, const float* __restrict__ w1,
                            const float* __restrict__ w2, const float* __restrict__ w3,
                            unsigned short* __restrict__ out) {
    const float* w;
    switch (blockIdx.y) { case 0: w = w0; break; case 1: w = w1; break;
                          case 2: w = w2; break; default: w = w3; }
    int fi = blockIdx.x;                    // 0..511
    int wv = fi >> 6, cf = (fi >> 3) & 7, kt = fi & 7;
    int lane = threadIdx.x;                 // 0..63
    int l16 = lane & 15, kqq = lane >> 4;
    int col = (cf & 3) * 256 + wv * 32 + (cf >> 2) * 16 + l16;
    int kbase = kt * 32 + kqq * 8;
    size_t obase = ((size_t)blockIdx.y * 512 + fi) * 512 + (size_t)lane * 8;
    #pragma unroll
    for (int e = 0; e < 8; ++e)
        out[obase + e] = f2u(w[(size_t)col * 256 + kbase + e]);
}

// Wt[n][k] = W[k][n], 640x640 zero-padded bf16
__global__ void k_prep_attw(const float* __restrict__ W, unsigned short* __restrict__ out) {
    int n = blockIdx.x;
    for (int k = threadIdx.x; k < 640; k += blockDim.x)
        out[(size_t)n * 640 + k] = (n < DATT && k < DATT) ? f2u(W[(size_t)k * DATT + n]) : (unsigned short)0;
}

// x = [emb[tok] | wpe[wpos] | 0pad] -> bf16 [32768][416]
__global__ void k_gather_x(const int* __restrict__ tok, const int* __restrict__ wpos,
                           const float* __restrict__ emb, const float* __restrict__ wpe,
                           unsigned short* __restrict__ x) {
    int i = blockIdx.x;
    int t = tok[i], p = wpos[i];
    const float* er = emb + (size_t)t * E_;
    const float* pr = wpe + (size_t)p * P_;
    unsigned short* xr = x + (size_t)i * 416;
    for (int c = threadIdx.x; c < 416; c += blockDim.x) {
        float v = (c < E_) ? er[c] : (c < 400 ? pr[c - E_] : 0.f);
        xr[c] = f2u(v);
    }
}

// ---------------------------------------------------------------------------
// MFMA GEMM: C[M][2048] = bf16(A[M][lda] @ W[2048][lda]^T + bias)
// 128x128 tile, BK=32, 256 threads (2x2 waves, each 64x64)
// ---------------------------------------------------------------------------
__global__ __launch_bounds__(256) void k_gemm_bias(
        const unsigned short* __restrict__ A, int lda,
        const unsigned short* __restrict__ W, const float* __restrict__ bias,
        unsigned short* __restrict__ C, int nkt) {
    __shared__ __align__(16) unsigned short As[128][40];
    __shared__ __align__(16) unsigned short Bs[128][40];
    int tid = threadIdx.x;
    int lane = tid & 63, wave = tid >> 6;
    int wm = wave >> 1, wn = wave & 1;
    int i0 = blockIdx.y * 128, n0 = blockIdx.x * 128;
    f32x4 acc[4][4] = {};
    int r = tid >> 2, kc = (tid & 3) * 8;
    for (int kt = 0; kt < nkt; ++kt) {
        int k0 = kt * 32;
        #pragma unroll
        for (int p = 0; p < 2; ++p) {
            int rr = r + p * 64;
            *(i32x4*)&As[rr][kc] = *(const i32x4*)&A[(size_t)(i0 + rr) * lda + k0 + kc];
            *(i32x4*)&Bs[rr][kc] = *(const i32x4*)&W[(size_t)(n0 + rr) * lda + k0 + kc];
        }
        __syncthreads();
        bf16x8 a[4], b[4];
        int arow = wm * 64 + (lane & 15);
        int brow = wn * 64 + (lane & 15);
        int kq = (lane >> 4) * 8;
        #pragma unroll
        for (int mi = 0; mi < 4; ++mi) a[mi] = *(const bf16x8*)&As[arow + mi * 16][kq];
        #pragma unroll
        for (int nj = 0; nj < 4; ++nj) b[nj] = *(const bf16x8*)&Bs[brow + nj * 16][kq];
        #pragma unroll
        for (int mi = 0; mi < 4; ++mi)
            #pragma unroll
            for (int nj = 0; nj < 4; ++nj)
                acc[mi][nj] = __builtin_amdgcn_mfma_f32_16x16x32_bf16(a[mi], b[nj], acc[mi][nj], 0, 0, 0);
        __syncthreads();
    }
    int q = lane >> 4;
    #pragma unroll
    for (int nj = 0; nj < 4; ++nj) {
        int col = n0 + wn * 64 + nj * 16 + (lane & 15);
        float bb = bias[col];
        #pragma unroll
        for (int mi = 0; mi < 4; ++mi)
            #pragma unroll
            for (int rr2 = 0; rr2 < 4; ++rr2) {
                int grow = i0 + wm * 64 + mi * 16 + q * 4 + rr2;
                C[(size_t)grow * 2048 + col] = f2u(acc[mi][nj][rr2] + bb);
            }
    }
}

// ---------------------------------------------------------------------------
// MFMA attention score: score[i] += proj . tanh(z[i] @ W + bias) over 128-col slice
// ---------------------------------------------------------------------------
__global__ __launch_bounds__(256) void k_attn_mfma(
        const unsigned short* __restrict__ Hsrc,
        const unsigned short* __restrict__ xpos,   // mode0: [M][416], pos at col 300
        const float* __restrict__ spe, const int* __restrict__ spos,  // mode1
        const unsigned short* __restrict__ Wt,     // [640][640] bf16 (n-major)
        const float* __restrict__ bias, const float* __restrict__ proj,
        float* __restrict__ score, int mode) {
    __shared__ __align__(16) unsigned short As[128][40];
    __shared__ __align__(16) unsigned short Bs[128][40];
    int tid = threadIdx.x;
    int lane = tid & 63, wave = tid >> 6;
    int wm = wave >> 1, wn = wave & 1;
    int i0 = blockIdx.y * 128, n0 = blockIdx.x * 128;
    f32x4 acc[4][4] = {};
    int r = tid >> 2, kc = (tid & 3) * 8;
    for (int kt = 0; kt < 20; ++kt) {
        int k0 = kt * 32;
        #pragma unroll
        for (int p = 0; p < 2; ++p) {
            int rr = r + p * 64;
            if (kt < 16) {
                *(i32x4*)&As[rr][kc] = *(const i32x4*)&Hsrc[(size_t)(i0 + rr) * 512 + k0 + kc];
            } else {
                int grow = i0 + rr;
                #pragma unroll
                for (int e = 0; e < 8; ++e) {
                    int k = k0 + kc + e;
                    int pp = k - 512;
                    unsigned short v = 0;
                    if (pp < P_) {
                        if (mode == 0) v = xpos[(size_t)grow * 416 + 300 + pp];
                        else           v = f2u(spe[(size_t)spos[grow] * P_ + pp]);
                    }
                    As[rr][kc + e] = v;
                }
            }
            *(i32x4*)&Bs[rr][kc] = *(const i32x4*)&Wt[(size_t)(n0 + rr) * 640 + k0 + kc];
        }
        __syncthreads();
        bf16x8 a[4], b[4];
        int arow = wm * 64 + (lane & 15);
        int brow = wn * 64 + (lane & 15);
        int kq = (lane >> 4) * 8;
        #pragma unroll
        for (int mi = 0; mi < 4; ++mi) a[mi] = *(const bf16x8*)&As[arow + mi * 16][kq];
        #pragma unroll
        for (int nj = 0; nj < 4; ++nj) b[nj] = *(const bf16x8*)&Bs[brow + nj * 16][kq];
        #pragma unroll
        for (int mi = 0; mi < 4; ++mi)
            #pragma unroll
            for (int nj = 0; nj < 4; ++nj)
                acc[mi][nj] = __builtin_amdgcn_mfma_f32_16x16x32_bf16(a[mi], b[nj], acc[mi][nj], 0, 0, 0);
        __syncthreads();
    }
    float srow[4][4] = {};
    int q = lane >> 4;
    #pragma unroll
    for (int nj = 0; nj < 4; ++nj) {
        int col = n0 + wn * 64 + nj * 16 + (lane & 15);
        if (col < DATT) {
            float bb = bias[col], pp = proj[col];
            #pragma unroll
            for (int mi = 0; mi < 4; ++mi)
                #pragma unroll
                for (int rr2 = 0; rr2 < 4; ++rr2)
                    srow[mi][rr2] += pp * tanh_f(acc[mi][nj][rr2] + bb);
        }
    }
    #pragma unroll
    for (int mi = 0; mi < 4; ++mi)
        #pragma unroll
        for (int rr2 = 0; rr2 < 4; ++rr2) {
            float v = srow[mi][rr2];
            v += __shfl_xor(v, 1); v += __shfl_xor(v, 2);
            v += __shfl_xor(v, 4); v += __shfl_xor(v, 8);
            if ((lane & 15) == 0)
                atomicAdd(&score[i0 + wm * 64 + mi * 16 + q * 4 + rr2], v);
        }
}

// ---------------------------------------------------------------------------
// Weight-resident LSTM. One INDEPENDENT block per (4-seq group, direction).
// 512 threads = 8 waves; wave owns 32 units x 4 gates = 128 gate-cols.
// Whh slice: 46 fragments in VGPRs + 18 fragments in LDS (144KB).
// h (4 seqs x 256) exchanged via one 2.6KB LDS buffer, 2 barriers/step.
// gpre prefetched global->reg one step ahead, parked in LDS before use.
// LDS: [0,147456) weights | [147456,155648) gpre [4][1024] | [155648,158288) h[5][264]
// ---------------------------------------------------------------------------
__global__ __launch_bounds__(512, 2) void k_lstm_res(
        const unsigned short* __restrict__ g,     // [(seq)*T+t][2048] bf16
        const unsigned short* __restrict__ whhr,  // level base: [2][512 frags][512]
        unsigned short* __restrict__ out,         // [(seq)*T+t][512] bf16
        float* __restrict__ finalh,               // optional, stride 1024
        int T) {
    extern __shared__ __align__(16) char smem[];
    char* wlds = smem;
    unsigned short* gpre = (unsigned short*)(smem + 147456);
    unsigned short* hbuf = (unsigned short*)(smem + 155648);
    const int tid = threadIdx.x;
    const int lane = tid & 63, w = tid >> 6;
    const int l16 = lane & 15, kq = lane >> 4;
    const int dir = blockIdx.y;
    const int seq0 = blockIdx.x * 4;
    const unsigned short* wsrc = whhr + (size_t)dir * (512 * 512);

    // zero h rows (5 x 264; row 4 stays zero = padding row for MFMA rows 4..15)
    for (int i = tid; i < 5 * 264; i += 512) hbuf[i] = 0;

    // stage weights: frag FI = cf*8+kt; FI<46 -> regs, else LDS
    bf16x8 wreg[46];
    char* wlds_w = wlds + w * 18432;
    #pragma unroll
    for (int cf = 0; cf < 8; ++cf) {
        #pragma unroll
        for (int kt = 0; kt < 8; ++kt) {
            const int FI = cf * 8 + kt;
            const unsigned short* src = wsrc + ((size_t)(w * 8 + cf) * 8 + kt) * 512 + (size_t)lane * 8;
            if (FI < 46) wreg[FI] = *(const bf16x8*)src;
            else *(i32x4*)(wlds_w + (FI - 46) * 1024 + lane * 16) = *(const i32x4*)src;
        }
    }
    float c[2][4] = {};
    // prefetch gpre for t=0
    const int gseq = tid >> 7, gcol = (tid & 127) * 8;
    i32x4 gld = *(const i32x4*)&g[((size_t)(seq0 + gseq) * T + (dir ? (T - 1) : 0)) * 2048
                                  + dir * 1024 + gcol];
    __syncthreads();

    const char* hrow = (const char*)hbuf + (l16 < 4 ? l16 : 4) * 528 + kq * 16;
    for (int t = 0; t < T; ++t) {
        const int ti = dir ? (T - 1 - t) : t;
        // MFMA: recurrent gates = h(t-1) @ Whh^T (t=0: h=0 -> acc=0)
        f32x4 acc[8] = {};
        #pragma unroll
        for (int kt = 0; kt < 8; ++kt) {
            bf16x8 a = *(const bf16x8*)(hrow + kt * 64);
            #pragma unroll
            for (int cf = 0; cf < 8; ++cf) {
                const int FI = cf * 8 + kt;
                bf16x8 b;
                if (FI < 46) b = wreg[FI];
                else b = *(const bf16x8*)(wlds_w + (FI - 46) * 1024 + lane * 16);
                acc[cf] = __builtin_amdgcn_mfma_f32_16x16x32_bf16(a, b, acc[cf], 0, 0, 0);
            }
        }
        // park gpre_t in LDS
        *(i32x4*)&gpre[gseq * 1024 + gcol] = gld;
        __syncthreads();   // B1: gpre visible; all h reads done
        // cell update: q==0 lanes own (2 units x 4 gates x 4 seqs) in-register
        if (kq == 0) {
            bool last = (t == T - 1);
            #pragma unroll
            for (int u16 = 0; u16 < 2; ++u16) {
                const int u = w * 32 + u16 * 16 + l16;
                #pragma unroll
                for (int rr = 0; rr < 4; ++rr) {
                    float ig = acc[u16 * 4 + 0][rr] + u2f(gpre[rr * 1024 + u]);
                    float fg = acc[u16 * 4 + 1][rr] + u2f(gpre[rr * 1024 + 256 + u]);
                    float gg = acc[u16 * 4 + 2][rr] + u2f(gpre[rr * 1024 + 512 + u]);
                    float og = acc[u16 * 4 + 3][rr] + u2f(gpre[rr * 1024 + 768 + u]);
                    ig = sigm(ig); fg = sigm(fg); gg = tanh_f(gg); og = sigm(og);
                    c[u16][rr] = fg * c[u16][rr] + ig * gg;
                    float hn = og * tanh_f(c[u16][rr]);
                    unsigned short hnb = f2u(hn);
                    hbuf[rr * 264 + u] = hnb;
                    out[((size_t)(seq0 + rr) * T + ti) * 512 + dir * 256 + u] = hnb;
                    if (finalh && last)
                        finalh[(size_t)(seq0 + rr) * 1024 + dir * 256 + u] = hn;
                }
            }
        }
        __syncthreads();   // B2: h(t) visible; gpre reads done
        if (t + 1 < T) {
            const int tn = dir ? (T - 2 - t) : (t + 1);
            gld = *(const i32x4*)&g[((size_t)(seq0 + gseq) * T + tn) * 2048 + dir * 1024 + gcol];
        }
    }
}

// ---------------------------------------------------------------------------
// word softmax over L=64 + pool -> sx = [sen_vec | spe | 0] bf16 [512][640]
// ---------------------------------------------------------------------------
__global__ void k_pool_word(const float* __restrict__ score, const unsigned short* __restrict__ sen_out,
                            const float* __restrict__ spe, const int* __restrict__ spos,
                            unsigned short* __restrict__ sx) {
    int n = blockIdx.x, tid = threadIdx.x;
    __shared__ float a_lds[64];
    if (tid < 64) {
        float sc = score[n * 64 + tid];
        float m = sc;
        #pragma unroll
        for (int off = 32; off >= 1; off >>= 1) m = fmaxf(m, __shfl_xor(m, off));
        float e = __expf(sc - m);
        float s = e;
        #pragma unroll
        for (int off = 32; off >= 1; off >>= 1) s += __shfl_xor(s, off);
        a_lds[tid] = e / s;
    }
    __syncthreads();
    for (int h = tid; h < 512; h += blockDim.x) {
        float acc = 0.f;
        const unsigned short* base = sen_out + (size_t)n * 64 * 512 + h;
        #pragma unroll 8
        for (int t = 0; t < 64; ++t) acc += a_lds[t] * u2f(base[(size_t)t * 512]);
        sx[(size_t)n * 640 + h] = f2u(acc);
    }
    int sp = spos[n];
    for (int p2 = tid; p2 < 128; p2 += blockDim.x)
        sx[(size_t)n * 640 + 512 + p2] = (p2 < P_) ? f2u(spe[(size_t)sp * P_ + p2]) : (unsigned short)0;
}

// sentence softmax over S=16 + pool -> feats[:, 0:512]
__global__ void k_pool_sent(const float* __restrict__ score, const unsigned short* __restrict__ doc_out,
                            float* __restrict__ feats) {
    int n = blockIdx.x, tid = threadIdx.x;
    __shared__ float a_lds[16];
    if (tid < 16) {
        float sc = score[n * 16 + tid];
        float m = sc;
        #pragma unroll
        for (int off = 8; off >= 1; off >>= 1) m = fmaxf(m, __shfl_xor(m, off));
        float e = __expf(sc - m);
        float s = e;
        #pragma unroll
        for (int off = 8; off >= 1; off >>= 1) s += __shfl_xor(s, off);
        a_lds[tid] = e / s;
    }
    __syncthreads();
    for (int h = tid; h < 512; h += blockDim.x) {
        float acc = 0.f;
        const unsigned short* base = doc_out + (size_t)n * 16 * 512 + h;
        #pragma unroll
        for (int t = 0; t < 16; ++t) acc += a_lds[t] * u2f(base[(size_t)t * 512]);
        feats[(size_t)n * 1024 + h] = acc;
    }
}

__global__ void k_dense(const float* __restrict__ feats, const float* __restrict__ W,
                        const float* __restrict__ bias, float* __restrict__ out) {
    int b = blockIdx.x, lane = threadIdx.x;
    for (int p = 0; p < 3; ++p) {
        float acc = 0.f;
        for (int k = lane; k < 1024; k += 64)
            acc += feats[(size_t)b * 1024 + k] * W[(size_t)p * 1024 + k];
        #pragma unroll
        for (int off = 32; off >= 1; off >>= 1) acc += __shfl_xor(acc, off);
        if (lane == 0) out[b * 3 + p] = acc + bias[p];
    }
}

// ---------------------------------------------------------------------------
extern "C" void kernel_launch(void* const* d_in, const int* in_sizes, int n_in,
                              void* d_out, int out_size, void* d_ws, size_t ws_size,
                              hipStream_t stream) {
    const int*   tok    = (const int*)d_in[0];
    const int*   wpos   = (const int*)d_in[1];
    const int*   spos   = (const int*)d_in[2];
    const float* emb    = (const float*)d_in[3];
    const float* wpet   = (const float*)d_in[4];
    const float* spet   = (const float*)d_in[5];
    const float* wWih_f = (const float*)d_in[6];
    const float* wWhh_f = (const float*)d_in[7];
    const float* wb_f   = (const float*)d_in[8];
    const float* wWih_b = (const float*)d_in[9];
    const float* wWhh_b = (const float*)d_in[10];
    const float* wb_b   = (const float*)d_in[11];
    const float* sWih_f = (const float*)d_in[12];
    const float* sWhh_f = (const float*)d_in[13];
    const float* sb_f   = (const float*)d_in[14];
    const float* sWih_b = (const float*)d_in[15];
    const float* sWhh_b = (const float*)d_in[16];
    const float* sb_b   = (const float*)d_in[17];
    const float* word_W = (const float*)d_in[18];
    const float* word_bias = (const float*)d_in[19];
    const float* word_proj = (const float*)d_in[20];
    const float* sent_W = (const float*)d_in[21];
    const float* sent_bias = (const float*)d_in[22];
    const float* sent_proj = (const float*)d_in[23];
    const float* dense_W = (const float*)d_in[24];
    const float* dense_b = (const float*)d_in[25];

    char* p = (char*)d_ws;
    auto alloc = [&](size_t bytes) -> void* {
        void* r = (void*)p;
        p += (bytes + 255) & ~(size_t)255;
        return r;
    };
    unsigned short* x_bf    = (unsigned short*)alloc((size_t)M1 * 416 * 2);
    unsigned short* g_bf    = (unsigned short*)alloc((size_t)M1 * 2048 * 2);
    unsigned short* sen_out = (unsigned short*)alloc((size_t)M1 * 512 * 2);
    float*          scores  = (float*)alloc((size_t)(M1 + NS) * 4);
    unsigned short* sx      = (unsigned short*)alloc((size_t)NS * 640 * 2);
    unsigned short* sg      = (unsigned short*)alloc((size_t)NS * 2048 * 2);
    unsigned short* doc_out = (unsigned short*)alloc((size_t)NS * 512 * 2);
    float*          feats   = (float*)alloc((size_t)B_ * 1024 * 4);
    unsigned short* wih_w   = (unsigned short*)alloc((size_t)2048 * 416 * 2);
    unsigned short* wih_s   = (unsigned short*)alloc((size_t)2048 * 640 * 2);
    float*          bias_w  = (float*)alloc(2048 * 4);
    float*          bias_s  = (float*)alloc(2048 * 4);
    unsigned short* whh_r   = (unsigned short*)alloc((size_t)4 * 512 * 512 * 2); // 2MB, frag-order
    unsigned short* attw_w  = (unsigned short*)alloc((size_t)640 * 640 * 2);
    unsigned short* attw_s  = (unsigned short*)alloc((size_t)640 * 640 * 2);
    float* wscore = scores;
    float* sscore = scores + M1;

    // ---- prep (all independent) ----
    hipMemsetAsync(scores, 0, (size_t)(M1 + NS) * 4, stream);
    k_prep_wih<<<2048, 256, 0, stream>>>(wWih_f, wWih_b, 400, 416, wih_w);
    k_prep_wih<<<2048, 256, 0, stream>>>(sWih_f, sWih_b, 612, 640, wih_s);
    k_cat_bias<<<8, 256, 0, stream>>>(wb_f, wb_b, bias_w);
    k_cat_bias<<<8, 256, 0, stream>>>(sb_f, sb_b, bias_s);
    k_prep_whhr<<<dim3(512, 4), 64, 0, stream>>>(wWhh_f, wWhh_b, sWhh_f, sWhh_b, whh_r);
    k_prep_attw<<<640, 256, 0, stream>>>(word_W, attw_w);
    k_prep_attw<<<640, 256, 0, stream>>>(sent_W, attw_s);
    k_gather_x<<<M1, 256, 0, stream>>>(tok, wpos, emb, wpet, x_bf);

    const unsigned int lstm_lds = 147456 + 8192 + 5 * 264 * 2;   // 158288 B

    // ---- word level ----
    k_gemm_bias<<<dim3(16, 256), 256, 0, stream>>>(x_bf, 416, wih_w, bias_w, g_bf, 13);
    k_lstm_res<<<dim3(128, 2), 512, lstm_lds, stream>>>(g_bf, whh_r, sen_out, nullptr, L_);
    k_attn_mfma<<<dim3(5, 256), 256, 0, stream>>>(sen_out, x_bf, nullptr, nullptr,
                                                  attw_w, word_bias, word_proj, wscore, 0);
    k_pool_word<<<512, 256, 0, stream>>>(wscore, sen_out, spet, spos, sx);

    // ---- sentence level ----
    k_gemm_bias<<<dim3(16, 4), 256, 0, stream>>>(sx, 640, wih_s, bias_s, sg, 20);
    k_lstm_res<<<dim3(8, 2), 512, lstm_lds, stream>>>(sg, whh_r + (size_t)2 * 512 * 512,
                                                      doc_out, feats + 512, S_);
    k_attn_mfma<<<dim3(5, 4), 256, 0, stream>>>(doc_out, nullptr, spet, spos,
                                                attw_s, sent_bias, sent_proj, sscore, 1);
    k_pool_sent<<<32, 256, 0, stream>>>(sscore, doc_out, feats);

    // ---- classifier ----
    k_dense<<<32, 64, 0, stream>>>(feats, dense_W, dense_b, (float*)d_out);
}

// Round 6
// 736.941 us; speedup vs baseline: 2.6499x; 1.2007x over previous
//
#include <hip/hip_runtime.h>
#include <hip/hip_bf16.h>

// Problem constants
#define B_    32
#define S_    16
#define L_    64
#define E_    300
#define P_    100
#define H_    256
#define DATT  612
#define NS    512      // B*S
#define M1    32768    // NS*L

typedef __hip_bfloat16 hbf;
typedef __attribute__((ext_vector_type(8))) short bf16x8;
typedef __attribute__((ext_vector_type(4))) float f32x4;
typedef __attribute__((ext_vector_type(4))) int i32x4;

__device__ __forceinline__ float u2f(unsigned short u) {
    unsigned int x = ((unsigned int)u) << 16;
    return __builtin_bit_cast(float, x);
}
__device__ __forceinline__ unsigned short f2u(float f) {
    return __builtin_bit_cast(unsigned short, __float2bfloat16(f));
}
__device__ __forceinline__ float sigm(float x) { return 1.0f / (1.0f + __expf(-x)); }
__device__ __forceinline__ float tanh_f(float x) {
    return 1.0f - 2.0f / (__expf(2.0f * x) + 1.0f);
}

// ---------------------------------------------------------------------------
// Prep: Wih concat [2048][Kdst] bf16 (rows 0..1023 fwd, 1024..2047 bwd), 0-pad K
// ---------------------------------------------------------------------------
__global__ void k_prep_wih(const float* __restrict__ wf, const float* __restrict__ wb,
                           int Ksrc, int Kdst, unsigned short* __restrict__ out) {
    int j = blockIdx.x;
    const float* src = (j < 1024) ? (wf + (size_t)j * Ksrc) : (wb + (size_t)(j - 1024) * Ksrc);
    unsigned short* o = out + (size_t)j * Kdst;
    for (int c = threadIdx.x; c < Kdst; c += blockDim.x)
        o[c] = (c < Ksrc) ? f2u(src[c]) : (unsigned short)0;
}

__global__ void k_cat_bias(const float* __restrict__ a, const float* __restrict__ b,
                           float* __restrict__ dst) {
    int i = blockIdx.x * 256 + threadIdx.x;   // 0..2047
    dst[i] = (i < 1024) ? a[i] : b[i - 1024];
}

// ---------------------------------------------------------------------------
// Prep Whh into per-(wave,colfrag,ktile) MFMA-fragment order for the 4-wave
// LSTM: fi = wv*128 + cf*8 + kt (wv 0..3, cf = u16*4+g 0..15, kt 0..7)
//   col = (cf&3)*256 + wv*64 + (cf>>2)*16 + (lane&15)
//   k   = kt*32 + (lane>>4)*8 + e
// out[(slot*512 + fi)*512 + lane*8 + e] = Whh[col][k]
// ---------------------------------------------------------------------------
__global__ void k_prep_whhr(const float* __restrict__ w0, const float* __restrict__ w1,
                            const float* __restrict__ w2, const float* __restrict__ w3,
                            unsigned short* __restrict__ out) {
    const float* w;
    switch (blockIdx.y) { case 0: w = w0; break; case 1: w = w1; break;
                          case 2: w = w2; break; default: w = w3; }
    int fi = blockIdx.x;                    // 0..511
    int wv = fi >> 7, cf = (fi >> 3) & 15, kt = fi & 7;
    int lane = threadIdx.x;                 // 0..63
    int l16 = lane & 15, kqq = lane >> 4;
    int col = (cf & 3) * 256 + wv * 64 + (cf >> 2) * 16 + l16;
    int kbase = kt * 32 + kqq * 8;
    size_t obase = ((size_t)blockIdx.y * 512 + fi) * 512 + (size_t)lane * 8;
    #pragma unroll
    for (int e = 0; e < 8; ++e)
        out[obase + e] = f2u(w[(size_t)col * 256 + kbase + e]);
}

// Wt[n][k] = W[k][n], 640x640 zero-padded bf16
__global__ void k_prep_attw(const float* __restrict__ W, unsigned short* __restrict__ out) {
    int n = blockIdx.x;
    for (int k = threadIdx.x; k < 640; k += blockDim.x)
        out[(size_t)n * 640 + k] = (n < DATT && k < DATT) ? f2u(W[(size_t)k * DATT + n]) : (unsigned short)0;
}

// x = [emb[tok] | wpe[wpos] | 0pad] -> bf16 [32768][416]
__global__ void k_gather_x(const int* __restrict__ tok, const int* __restrict__ wpos,
                           const float* __restrict__ emb, const float* __restrict__ wpe,
                           unsigned short* __restrict__ x) {
    int i = blockIdx.x;
    int t = tok[i], p = wpos[i];
    const float* er = emb + (size_t)t * E_;
    const float* pr = wpe + (size_t)p * P_;
    unsigned short* xr = x + (size_t)i * 416;
    for (int c = threadIdx.x; c < 416; c += blockDim.x) {
        float v = (c < E_) ? er[c] : (c < 400 ? pr[c - E_] : 0.f);
        xr[c] = f2u(v);
    }
}

// ---------------------------------------------------------------------------
// MFMA GEMM: C[M][2048] = bf16(A[M][lda] @ W[2048][lda]^T + bias)
// 128x128 tile, BK=32, 256 threads (2x2 waves, each 64x64)
// ---------------------------------------------------------------------------
__global__ __launch_bounds__(256) void k_gemm_bias(
        const unsigned short* __restrict__ A, int lda,
        const unsigned short* __restrict__ W, const float* __restrict__ bias,
        unsigned short* __restrict__ C, int nkt) {
    __shared__ __align__(16) unsigned short As[128][40];
    __shared__ __align__(16) unsigned short Bs[128][40];
    int tid = threadIdx.x;
    int lane = tid & 63, wave = tid >> 6;
    int wm = wave >> 1, wn = wave & 1;
    int i0 = blockIdx.y * 128, n0 = blockIdx.x * 128;
    f32x4 acc[4][4] = {};
    int r = tid >> 2, kc = (tid & 3) * 8;
    for (int kt = 0; kt < nkt; ++kt) {
        int k0 = kt * 32;
        #pragma unroll
        for (int p = 0; p < 2; ++p) {
            int rr = r + p * 64;
            *(i32x4*)&As[rr][kc] = *(const i32x4*)&A[(size_t)(i0 + rr) * lda + k0 + kc];
            *(i32x4*)&Bs[rr][kc] = *(const i32x4*)&W[(size_t)(n0 + rr) * lda + k0 + kc];
        }
        __syncthreads();
        bf16x8 a[4], b[4];
        int arow = wm * 64 + (lane & 15);
        int brow = wn * 64 + (lane & 15);
        int kq = (lane >> 4) * 8;
        #pragma unroll
        for (int mi = 0; mi < 4; ++mi) a[mi] = *(const bf16x8*)&As[arow + mi * 16][kq];
        #pragma unroll
        for (int nj = 0; nj < 4; ++nj) b[nj] = *(const bf16x8*)&Bs[brow + nj * 16][kq];
        #pragma unroll
        for (int mi = 0; mi < 4; ++mi)
            #pragma unroll
            for (int nj = 0; nj < 4; ++nj)
                acc[mi][nj] = __builtin_amdgcn_mfma_f32_16x16x32_bf16(a[mi], b[nj], acc[mi][nj], 0, 0, 0);
        __syncthreads();
    }
    int q = lane >> 4;
    #pragma unroll
    for (int nj = 0; nj < 4; ++nj) {
        int col = n0 + wn * 64 + nj * 16 + (lane & 15);
        float bb = bias[col];
        #pragma unroll
        for (int mi = 0; mi < 4; ++mi)
            #pragma unroll
            for (int rr2 = 0; rr2 < 4; ++rr2) {
                int grow = i0 + wm * 64 + mi * 16 + q * 4 + rr2;
                C[(size_t)grow * 2048 + col] = f2u(acc[mi][nj][rr2] + bb);
            }
    }
}

// ---------------------------------------------------------------------------
// MFMA attention score: score[i] += proj . tanh(z[i] @ W + bias) over 128-col slice
// ---------------------------------------------------------------------------
__global__ __launch_bounds__(256) void k_attn_mfma(
        const unsigned short* __restrict__ Hsrc,
        const unsigned short* __restrict__ xpos,   // mode0: [M][416], pos at col 300
        const float* __restrict__ spe, const int* __restrict__ spos,  // mode1
        const unsigned short* __restrict__ Wt,     // [640][640] bf16 (n-major)
        const float* __restrict__ bias, const float* __restrict__ proj,
        float* __restrict__ score, int mode) {
    __shared__ __align__(16) unsigned short As[128][40];
    __shared__ __align__(16) unsigned short Bs[128][40];
    int tid = threadIdx.x;
    int lane = tid & 63, wave = tid >> 6;
    int wm = wave >> 1, wn = wave & 1;
    int i0 = blockIdx.y * 128, n0 = blockIdx.x * 128;
    f32x4 acc[4][4] = {};
    int r = tid >> 2, kc = (tid & 3) * 8;
    for (int kt = 0; kt < 20; ++kt) {
        int k0 = kt * 32;
        #pragma unroll
        for (int p = 0; p < 2; ++p) {
            int rr = r + p * 64;
            if (kt < 16) {
                *(i32x4*)&As[rr][kc] = *(const i32x4*)&Hsrc[(size_t)(i0 + rr) * 512 + k0 + kc];
            } else {
                int grow = i0 + rr;
                #pragma unroll
                for (int e = 0; e < 8; ++e) {
                    int k = k0 + kc + e;
                    int pp = k - 512;
                    unsigned short v = 0;
                    if (pp < P_) {
                        if (mode == 0) v = xpos[(size_t)grow * 416 + 300 + pp];
                        else           v = f2u(spe[(size_t)spos[grow] * P_ + pp]);
                    }
                    As[rr][kc + e] = v;
                }
            }
            *(i32x4*)&Bs[rr][kc] = *(const i32x4*)&Wt[(size_t)(n0 + rr) * 640 + k0 + kc];
        }
        __syncthreads();
        bf16x8 a[4], b[4];
        int arow = wm * 64 + (lane & 15);
        int brow = wn * 64 + (lane & 15);
        int kq = (lane >> 4) * 8;
        #pragma unroll
        for (int mi = 0; mi < 4; ++mi) a[mi] = *(const bf16x8*)&As[arow + mi * 16][kq];
        #pragma unroll
        for (int nj = 0; nj < 4; ++nj) b[nj] = *(const bf16x8*)&Bs[brow + nj * 16][kq];
        #pragma unroll
        for (int mi = 0; mi < 4; ++mi)
            #pragma unroll
            for (int nj = 0; nj < 4; ++nj)
                acc[mi][nj] = __builtin_amdgcn_mfma_f32_16x16x32_bf16(a[mi], b[nj], acc[mi][nj], 0, 0, 0);
        __syncthreads();
    }
    float srow[4][4] = {};
    int q = lane >> 4;
    #pragma unroll
    for (int nj = 0; nj < 4; ++nj) {
        int col = n0 + wn * 64 + nj * 16 + (lane & 15);
        if (col < DATT) {
            float bb = bias[col], pp = proj[col];
            #pragma unroll
            for (int mi = 0; mi < 4; ++mi)
                #pragma unroll
                for (int rr2 = 0; rr2 < 4; ++rr2)
                    srow[mi][rr2] += pp * tanh_f(acc[mi][nj][rr2] + bb);
        }
    }
    #pragma unroll
    for (int mi = 0; mi < 4; ++mi)
        #pragma unroll
        for (int rr2 = 0; rr2 < 4; ++rr2) {
            float v = srow[mi][rr2];
            v += __shfl_xor(v, 1); v += __shfl_xor(v, 2);
            v += __shfl_xor(v, 4); v += __shfl_xor(v, 8);
            if ((lane & 15) == 0)
                atomicAdd(&score[i0 + wm * 64 + mi * 16 + q * 4 + rr2], v);
        }
}

// ---------------------------------------------------------------------------
// Weight-resident LSTM v2. One INDEPENDENT block per (4-seq group, direction).
// 256 threads = 4 waves, 1 wave/SIMD -> 512-VGPR budget per wave.
// Wave owns 64 units x 4 gates = 256 gate-cols = 128 fragments:
//   96 frags in VGPRs (384 regs) + 32 frags in LDS (32KB/wave, 128KB total).
// MFMA in 2 passes of 8 col-frags (acc = 32 regs live).
// Cell update spread over all 256 threads via gates[1024][4] f32 LDS exchange.
// LDS: [0,131072) weights | [131072,147456) gates f32[1024][4]
//      [147456,155648) gpre u16[4][1024] | [155648,158288) hbuf u16[5][264]
// ---------------------------------------------------------------------------
__global__ __launch_bounds__(256, 1) void k_lstm_res(
        const unsigned short* __restrict__ g,     // [(seq)*T+t][2048] bf16
        const unsigned short* __restrict__ whhr,  // level base: [2][512 frags][512]
        unsigned short* __restrict__ out,         // [(seq)*T+t][512] bf16
        float* __restrict__ finalh,               // optional, stride 1024
        int T) {
    extern __shared__ __align__(16) char smem[];
    char* wlds = smem;
    float* gates = (float*)(smem + 131072);
    unsigned short* gpre = (unsigned short*)(smem + 147456);
    unsigned short* hbuf = (unsigned short*)(smem + 155648);
    const int tid = threadIdx.x;
    const int lane = tid & 63, w = tid >> 6;
    const int l16 = lane & 15, kq = lane >> 4;
    const int dir = blockIdx.y;
    const int seq0 = blockIdx.x * 4;
    const unsigned short* wsrc = whhr + (size_t)dir * (512 * 512);

    // zero h rows (5 x 264; row 4 stays zero = MFMA pad row for A-rows 4..15)
    for (int i = tid; i < 5 * 264; i += 256) hbuf[i] = 0;

    // stage weights: fi = cf*8+kt in [0,128); fi<96 -> VGPR, else LDS
    bf16x8 wreg[96];
    char* wlds_w = wlds + w * 32768;
    #pragma unroll
    for (int cf = 0; cf < 16; ++cf) {
        #pragma unroll
        for (int kt = 0; kt < 8; ++kt) {
            const int fi = cf * 8 + kt;
            const unsigned short* src = wsrc + (((size_t)(w * 16 + cf) * 8 + kt) << 9) + (size_t)lane * 8;
            if (fi < 96) wreg[fi] = *(const bf16x8*)src;
            else *(i32x4*)(wlds_w + (fi - 96) * 1024 + lane * 16) = *(const i32x4*)src;
        }
    }
    float c[4] = {0.f, 0.f, 0.f, 0.f};

    // prefetch gpre for t=0: 2 chunks of 8 u16 per thread (4 seqs x 128 chunks)
    i32x4 gld[2];
    #pragma unroll
    for (int it = 0; it < 2; ++it) {
        int idx = tid + it * 256;
        int sq = idx >> 7, ch = idx & 127;
        gld[it] = *(const i32x4*)&g[((size_t)(seq0 + sq) * T + (dir ? T - 1 : 0)) * 2048
                                    + dir * 1024 + ch * 8];
    }
    __syncthreads();   // hbuf zeros visible

    const char* hrow = (const char*)hbuf + (l16 < 4 ? l16 : 4) * 528 + kq * 16;
    for (int t = 0; t < T; ++t) {
        const int ti = dir ? (T - 1 - t) : t;
        // park gpre(t) (safe: cell(t-1) finished reading gpre before last barrier)
        #pragma unroll
        for (int it = 0; it < 2; ++it) {
            int idx = tid + it * 256;
            int sq = idx >> 7, ch = idx & 127;
            *(i32x4*)&gpre[sq * 1024 + ch * 8] = gld[it];
        }
        // prefetch gpre(t+1) under the MFMA phase
        if (t + 1 < T) {
            const int tn = dir ? (T - 2 - t) : (t + 1);
            #pragma unroll
            for (int it = 0; it < 2; ++it) {
                int idx = tid + it * 256;
                int sq = idx >> 7, ch = idx & 127;
                gld[it] = *(const i32x4*)&g[((size_t)(seq0 + sq) * T + tn) * 2048
                                            + dir * 1024 + ch * 8];
            }
        }
        // recurrent matvec in 2 passes of 8 col-frags
        #pragma unroll
        for (int half = 0; half < 2; ++half) {
            f32x4 acc[8] = {};
            #pragma unroll
            for (int kt = 0; kt < 8; ++kt) {
                bf16x8 a = *(const bf16x8*)(hrow + kt * 64);
                #pragma unroll
                for (int cc = 0; cc < 8; ++cc) {
                    const int cf = half * 8 + cc;
                    const int fi = cf * 8 + kt;
                    bf16x8 b;
                    if (fi < 96) b = wreg[fi];
                    else b = *(const bf16x8*)(wlds_w + (fi - 96) * 1024 + lane * 16);
                    acc[cc] = __builtin_amdgcn_mfma_f32_16x16x32_bf16(a, b, acc[cc], 0, 0, 0);
                }
            }
            if (kq == 0) {   // rows 0..3 = seqs; write gates[col][0..3]
                #pragma unroll
                for (int cc = 0; cc < 8; ++cc) {
                    const int cf = half * 8 + cc;
                    int col = (cf & 3) * 256 + w * 64 + (cf >> 2) * 16 + l16;
                    *(f32x4*)&gates[col * 4] = acc[cc];
                }
            }
        }
        __syncthreads();   // B1: gates + gpre visible; all hbuf reads done
        // cell update: thread owns unit u for all 4 seqs
        {
            const int u = tid;
            f32x4 gi = *(const f32x4*)&gates[(0 * 256 + u) * 4];
            f32x4 gf = *(const f32x4*)&gates[(1 * 256 + u) * 4];
            f32x4 gc = *(const f32x4*)&gates[(2 * 256 + u) * 4];
            f32x4 go = *(const f32x4*)&gates[(3 * 256 + u) * 4];
            #pragma unroll
            for (int s = 0; s < 4; ++s) {
                float ig = gi[s] + u2f(gpre[s * 1024 + u]);
                float fg = gf[s] + u2f(gpre[s * 1024 + 256 + u]);
                float gv = gc[s] + u2f(gpre[s * 1024 + 512 + u]);
                float og = go[s] + u2f(gpre[s * 1024 + 768 + u]);
                ig = sigm(ig); fg = sigm(fg); gv = tanh_f(gv); og = sigm(og);
                c[s] = fg * c[s] + ig * gv;
                float hn = og * tanh_f(c[s]);
                unsigned short hnb = f2u(hn);
                hbuf[s * 264 + u] = hnb;
                out[((size_t)(seq0 + s) * T + ti) * 512 + dir * 256 + u] = hnb;
            }
        }
        __syncthreads();   // B2: h(t) visible; gpre reads done
    }
    if (finalh) {
        const int u = tid;
        #pragma unroll
        for (int s = 0; s < 4; ++s)
            finalh[(size_t)(seq0 + s) * 1024 + dir * 256 + u] = u2f(hbuf[s * 264 + u]);
    }
}

// ---------------------------------------------------------------------------
// word softmax over L=64 + pool -> sx = [sen_vec | spe | 0] bf16 [512][640]
// ---------------------------------------------------------------------------
__global__ void k_pool_word(const float* __restrict__ score, const unsigned short* __restrict__ sen_out,
                            const float* __restrict__ spe, const int* __restrict__ spos,
                            unsigned short* __restrict__ sx) {
    int n = blockIdx.x, tid = threadIdx.x;
    __shared__ float a_lds[64];
    if (tid < 64) {
        float sc = score[n * 64 + tid];
        float m = sc;
        #pragma unroll
        for (int off = 32; off >= 1; off >>= 1) m = fmaxf(m, __shfl_xor(m, off));
        float e = __expf(sc - m);
        float s = e;
        #pragma unroll
        for (int off = 32; off >= 1; off >>= 1) s += __shfl_xor(s, off);
        a_lds[tid] = e / s;
    }
    __syncthreads();
    for (int h = tid; h < 512; h += blockDim.x) {
        float acc = 0.f;
        const unsigned short* base = sen_out + (size_t)n * 64 * 512 + h;
        #pragma unroll 8
        for (int t = 0; t < 64; ++t) acc += a_lds[t] * u2f(base[(size_t)t * 512]);
        sx[(size_t)n * 640 + h] = f2u(acc);
    }
    int sp = spos[n];
    for (int p2 = tid; p2 < 128; p2 += blockDim.x)
        sx[(size_t)n * 640 + 512 + p2] = (p2 < P_) ? f2u(spe[(size_t)sp * P_ + p2]) : (unsigned short)0;
}

// sentence softmax over S=16 + pool -> feats[:, 0:512]
__global__ void k_pool_sent(const float* __restrict__ score, const unsigned short* __restrict__ doc_out,
                            float* __restrict__ feats) {
    int n = blockIdx.x, tid = threadIdx.x;
    __shared__ float a_lds[16];
    if (tid < 16) {
        float sc = score[n * 16 + tid];
        float m = sc;
        #pragma unroll
        for (int off = 8; off >= 1; off >>= 1) m = fmaxf(m, __shfl_xor(m, off));
        float e = __expf(sc - m);
        float s = e;
        #pragma unroll
        for (int off = 8; off >= 1; off >>= 1) s += __shfl_xor(s, off);
        a_lds[tid] = e / s;
    }
    __syncthreads();
    for (int h = tid; h < 512; h += blockDim.x) {
        float acc = 0.f;
        const unsigned short* base = doc_out + (size_t)n * 16 * 512 + h;
        #pragma unroll
        for (int t = 0; t < 16; ++t) acc += a_lds[t] * u2f(base[(size_t)t * 512]);
        feats[(size_t)n * 1024 + h] = acc;
    }
}

__global__ void k_dense(const float* __restrict__ feats, const float* __restrict__ W,
                        const float* __restrict__ bias, float* __restrict__ out) {
    int b = blockIdx.x, lane = threadIdx.x;
    for (int p = 0; p < 3; ++p) {
        float acc = 0.f;
        for (int k = lane; k < 1024; k += 64)
            acc += feats[(size_t)b * 1024 + k] * W[(size_t)p * 1024 + k];
        #pragma unroll
        for (int off = 32; off >= 1; off >>= 1) acc += __shfl_xor(acc, off);
        if (lane == 0) out[b * 3 + p] = acc + bias[p];
    }
}

// ---------------------------------------------------------------------------
extern "C" void kernel_launch(void* const* d_in, const int* in_sizes, int n_in,
                              void* d_out, int out_size, void* d_ws, size_t ws_size,
                              hipStream_t stream) {
    const int*   tok    = (const int*)d_in[0];
    const int*   wpos   = (const int*)d_in[1];
    const int*   spos   = (const int*)d_in[2];
    const float* emb    = (const float*)d_in[3];
    const float* wpet   = (const float*)d_in[4];
    const float* spet   = (const float*)d_in[5];
    const float* wWih_f = (const float*)d_in[6];
    const float* wWhh_f = (const float*)d_in[7];
    const float* wb_f   = (const float*)d_in[8];
    const float* wWih_b = (const float*)d_in[9];
    const float* wWhh_b = (const float*)d_in[10];
    const float* wb_b   = (const float*)d_in[11];
    const float* sWih_f = (const float*)d_in[12];
    const float* sWhh_f = (const float*)d_in[13];
    const float* sb_f   = (const float*)d_in[14];
    const float* sWih_b = (const float*)d_in[15];
    const float* sWhh_b = (const float*)d_in[16];
    const float* sb_b   = (const float*)d_in[17];
    const float* word_W = (const float*)d_in[18];
    const float* word_bias = (const float*)d_in[19];
    const float* word_proj = (const float*)d_in[20];
    const float* sent_W = (const float*)d_in[21];
    const float* sent_bias = (const float*)d_in[22];
    const float* sent_proj = (const float*)d_in[23];
    const float* dense_W = (const float*)d_in[24];
    const float* dense_b = (const float*)d_in[25];

    char* p = (char*)d_ws;
    auto alloc = [&](size_t bytes) -> void* {
        void* r = (void*)p;
        p += (bytes + 255) & ~(size_t)255;
        return r;
    };
    unsigned short* x_bf    = (unsigned short*)alloc((size_t)M1 * 416 * 2);
    unsigned short* g_bf    = (unsigned short*)alloc((size_t)M1 * 2048 * 2);
    unsigned short* sen_out = (unsigned short*)alloc((size_t)M1 * 512 * 2);
    float*          scores  = (float*)alloc((size_t)(M1 + NS) * 4);
    unsigned short* sx      = (unsigned short*)alloc((size_t)NS * 640 * 2);
    unsigned short* sg      = (unsigned short*)alloc((size_t)NS * 2048 * 2);
    unsigned short* doc_out = (unsigned short*)alloc((size_t)NS * 512 * 2);
    float*          feats   = (float*)alloc((size_t)B_ * 1024 * 4);
    unsigned short* wih_w   = (unsigned short*)alloc((size_t)2048 * 416 * 2);
    unsigned short* wih_s   = (unsigned short*)alloc((size_t)2048 * 640 * 2);
    float*          bias_w  = (float*)alloc(2048 * 4);
    float*          bias_s  = (float*)alloc(2048 * 4);
    unsigned short* whh_r   = (unsigned short*)alloc((size_t)4 * 512 * 512 * 2); // 2MB, frag-order
    unsigned short* attw_w  = (unsigned short*)alloc((size_t)640 * 640 * 2);
    unsigned short* attw_s  = (unsigned short*)alloc((size_t)640 * 640 * 2);
    float* wscore = scores;
    float* sscore = scores + M1;

    // ---- prep (all independent) ----
    hipMemsetAsync(scores, 0, (size_t)(M1 + NS) * 4, stream);
    k_prep_wih<<<2048, 256, 0, stream>>>(wWih_f, wWih_b, 400, 416, wih_w);
    k_prep_wih<<<2048, 256, 0, stream>>>(sWih_f, sWih_b, 612, 640, wih_s);
    k_cat_bias<<<8, 256, 0, stream>>>(wb_f, wb_b, bias_w);
    k_cat_bias<<<8, 256, 0, stream>>>(sb_f, sb_b, bias_s);
    k_prep_whhr<<<dim3(512, 4), 64, 0, stream>>>(wWhh_f, wWhh_b, sWhh_f, sWhh_b, whh_r);
    k_prep_attw<<<640, 256, 0, stream>>>(word_W, attw_w);
    k_prep_attw<<<640, 256, 0, stream>>>(sent_W, attw_s);
    k_gather_x<<<M1, 256, 0, stream>>>(tok, wpos, emb, wpet, x_bf);

    const unsigned int lstm_lds = 131072 + 16384 + 8192 + 5 * 264 * 2;   // 158288 B

    // ---- word level ----
    k_gemm_bias<<<dim3(16, 256), 256, 0, stream>>>(x_bf, 416, wih_w, bias_w, g_bf, 13);
    k_lstm_res<<<dim3(128, 2), 256, lstm_lds, stream>>>(g_bf, whh_r, sen_out, nullptr, L_);
    k_attn_mfma<<<dim3(5, 256), 256, 0, stream>>>(sen_out, x_bf, nullptr, nullptr,
                                                  attw_w, word_bias, word_proj, wscore, 0);
    k_pool_word<<<512, 256, 0, stream>>>(wscore, sen_out, spet, spos, sx);

    // ---- sentence level ----
    k_gemm_bias<<<dim3(16, 4), 256, 0, stream>>>(sx, 640, wih_s, bias_s, sg, 20);
    k_lstm_res<<<dim3(8, 2), 256, lstm_lds, stream>>>(sg, whh_r + (size_t)2 * 512 * 512,
                                                      doc_out, feats + 512, S_);
    k_attn_mfma<<<dim3(5, 4), 256, 0, stream>>>(doc_out, nullptr, spet, spos,
                                                attw_s, sent_bias, sent_proj, sscore, 1);
    k_pool_sent<<<32, 256, 0, stream>>>(sscore, doc_out, feats);

    // ---- classifier ----
    k_dense<<<32, 64, 0, stream>>>(feats, dense_W, dense_b, (float*)d_out);
}